// Round 11
// baseline (109.044 us; speedup 1.0000x reference)
//
#include <hip/hip_runtime.h>

#define NH 16
#define NT 16
#define DD 64
#define SS 1024
#define LL 1024
#define TOTK 2064
#define EE 1024
#define NWAVE 8

typedef __attribute__((ext_vector_type(8))) short bf16x8;
typedef __attribute__((ext_vector_type(4))) float f32x4;

__device__ __forceinline__ unsigned short f2bf(float x) {
  union { float f; unsigned u; } v; v.f = x;
  unsigned r = v.u + 0x7fffu + ((v.u >> 16) & 1u);
  return (unsigned short)(r >> 16);
}

// HW packed fp32->bf16 (RNE)
__device__ __forceinline__ unsigned pkbf(float a, float b) {
  unsigned r;
  asm("v_cvt_pk_bf16_f32 %0, %1, %2" : "=v"(r) : "v"(a), "v"(b));
  return r;
}
union BF8 { unsigned u[4]; bf16x8 v; };

// async global->LDS DMA, 16B/lane
__device__ __forceinline__ void dma16(const void* g, void* l) {
  __builtin_amdgcn_global_load_lds(
      (const __attribute__((address_space(1))) unsigned int*)g,
      (__attribute__((address_space(3))) unsigned int*)l, 16, 0, 0);
}

// ---------------- QKV projection (unchanged, validated) ----------------
__global__ __launch_bounds__(256)
void proj_kernel(const float* __restrict__ hidden,
                 const float* __restrict__ Wq, const float* __restrict__ bq,
                 const float* __restrict__ Wk, const float* __restrict__ bk,
                 const float* __restrict__ Wv, const float* __restrict__ bv,
                 unsigned short* __restrict__ qws,
                 float* __restrict__ kws, float* __restrict__ vws)
{
  __shared__ alignas(16) unsigned short As[64][72];
  __shared__ alignas(16) unsigned short Bs[64][72];
  const int mtile = blockIdx.x;
  const int ntile = blockIdx.y;
  const int mat = ntile >> 4;
  const int h = ntile & 15;
  const float* Wm = (mat == 0) ? Wq : (mat == 1 ? Wk : Wv);
  const float* bm = (mat == 0) ? bq : (mat == 1 ? bk : bv);
  const int tid = threadIdx.x;
  const int lane = tid & 63, w = tid >> 6;
  const int lr = lane & 15, lg = lane >> 4;
  const int m0 = mtile * 64;

  const f32x4 fz = {0.f, 0.f, 0.f, 0.f};
  f32x4 acc[4];
  #pragma unroll
  for (int j = 0; j < 4; ++j) acc[j] = fz;

  const int srow = tid >> 4, sc4 = tid & 15;
  float4 Ar[4], Br[4];
  #pragma unroll
  for (int it = 0; it < 4; ++it) {
    Ar[it] = *(const float4*)(hidden + (m0 + srow + it * 16) * EE + sc4 * 4);
    Br[it] = *(const float4*)(Wm + (h * 64 + srow + it * 16) * EE + sc4 * 4);
  }

  for (int k0 = 0; k0 < EE; k0 += 64) {
    __syncthreads();
    #pragma unroll
    for (int it = 0; it < 4; ++it) {
      int row = srow + it * 16;
      float4 a = Ar[it], b = Br[it];
      *(uint2*)(&As[row][sc4 * 4]) = make_uint2(pkbf(a.x, a.y), pkbf(a.z, a.w));
      *(uint2*)(&Bs[row][sc4 * 4]) = make_uint2(pkbf(b.x, b.y), pkbf(b.z, b.w));
    }
    __syncthreads();
    int kn = k0 + 64;
    if (kn < EE) {
      #pragma unroll
      for (int it = 0; it < 4; ++it) {
        Ar[it] = *(const float4*)(hidden + (m0 + srow + it * 16) * EE + kn + sc4 * 4);
        Br[it] = *(const float4*)(Wm + (h * 64 + srow + it * 16) * EE + kn + sc4 * 4);
      }
    }
    #pragma unroll
    for (int hh = 0; hh < 2; ++hh) {
      bf16x8 a = *(const bf16x8*)(&As[w * 16 + lr][hh * 32 + lg * 8]);
      #pragma unroll
      for (int dt = 0; dt < 4; ++dt) {
        bf16x8 b = *(const bf16x8*)(&Bs[dt * 16 + lr][hh * 32 + lg * 8]);
        acc[dt] = __builtin_amdgcn_mfma_f32_16x16x32_bf16(a, b, acc[dt], 0, 0, 0);
      }
    }
  }

  #pragma unroll
  for (int dt = 0; dt < 4; ++dt)
    #pragma unroll
    for (int r = 0; r < 4; ++r) {
      int Mrow = m0 + w * 16 + lg * 4 + r;
      int nb = Mrow >> 4, t = Mrow & 15;
      int d = dt * 16 + lr;
      float val = acc[dt][r] + bm[h * 64 + d];
      int oi = ((nb * NH + h) * NT + t) * DD + d;
      if (mat == 0) qws[oi] = f2bf(val);
      else if (mat == 1) kws[oi] = val;
      else vws[oi] = val;
    }
}

// ---------------- fused prefix attention: one deterministic wait per pair ----------------
// Steady-state vmcnt queue (oldest->newest) at pair top: [K-DMA(8) | rel(10)].
// vmcnt(10) retires exactly the DMA; rel stays (auto-wait at QK epilogue);
// V issued after the wait, retired by PV's auto vmcnt(18).
__global__ __launch_bounds__(512, 2)
void attn_kernel(const float* __restrict__ mask, const float* __restrict__ rel,
                 const float* __restrict__ ppk, const float* __restrict__ ppv,
                 const float* __restrict__ pk, const float* __restrict__ pv,
                 const unsigned short* __restrict__ qws,
                 const float* __restrict__ kws, const float* __restrict__ vws,
                 float* __restrict__ out)
{
  __shared__ __align__(16) float SB[2 * 128 * 64];           // 64 KB K dbuf
  __shared__ __align__(16) unsigned short Pb[NWAVE][16][40]; // 10 KB

  const int wg = blockIdx.x;
  const int nb = wg >> 4, h = wg & 15;
  const int n = nb >> 2;
  const int tid = threadIdx.x;
  const int lane = tid & 63, w = tid >> 6;
  const int lr = lane & 15, lg = lane >> 4;

  const unsigned short* qbase = qws + ((nb * NH + h) * NT) * DD;
  bf16x8 aq0 = *(const bf16x8*)(qbase + lr * DD + lg * 8);
  bf16x8 aq1 = *(const bf16x8*)(qbase + lr * DD + lg * 8 + 32);

  const float* relbase = rel + ((nb * NH + h) * NT) * TOTK;
  const float* mbase = mask + nb * TOTK;

  const f32x4 fz = {0.f, 0.f, 0.f, 0.f};
  f32x4 ctx[4];
  float ls[4];
  #pragma unroll
  for (int dt = 0; dt < 4; ++dt) ctx[dt] = fz;
  #pragma unroll
  for (int r = 0; r < 4; ++r) ls[r] = 0.f;

  auto kstage = [&](int c, int buf) {
    const float* ks = (c < 8)  ? ppk + ((n * NH + h) * SS + c * 128) * DD
                    : (c < 16) ? pk + ((nb * NH + h) * LL + (c - 8) * 128) * DD
                               : kws + ((nb * NH + h) * NT) * DD;
    float* Kb = SB + buf * 128 * 64;
    #pragma unroll
    for (int q = 0; q < 4; ++q) {
      int Lrow = w * 16 + q * 4 + (lane >> 4);
      int colb = (lane & 15) * 16;
      int scolb = colb ^ ((Lrow & 7) << 4);
      int srow = (c == 16) ? (Lrow & 15) : Lrow;
      dma16((const char*)ks + srow * 256 + scolb, Kb + (w * 16 + q * 4) * 64);
    }
  };

  auto qk_sub = [&](const float* Kb, const float rr[4], float mv, int sub) {
    bf16x8 kbf[2];
    #pragma unroll
    for (int hh = 0; hh < 2; ++hh) {
      int c0 = (hh * 128 + lg * 32) ^ ((lr & 7) << 4);
      int c1 = (hh * 128 + lg * 32 + 16) ^ ((lr & 7) << 4);
      float4 v0 = *(const float4*)((const char*)Kb + (w * 16 + lr) * 256 + c0);
      float4 v1 = *(const float4*)((const char*)Kb + (w * 16 + lr) * 256 + c1);
      BF8 o;
      o.u[0] = pkbf(v0.x, v0.y); o.u[1] = pkbf(v0.z, v0.w);
      o.u[2] = pkbf(v1.x, v1.y); o.u[3] = pkbf(v1.z, v1.w);
      kbf[hh] = o.v;
    }
    f32x4 s = fz;
    s = __builtin_amdgcn_mfma_f32_16x16x32_bf16(aq0, kbf[0], s, 0, 0, 0);
    s = __builtin_amdgcn_mfma_f32_16x16x32_bf16(aq1, kbf[1], s, 0, 0, 0);
    #pragma unroll
    for (int r = 0; r < 4; ++r) {
      float p = __expf(s[r] * 0.125f + rr[r] + mv);
      ls[r] += p;
      Pb[w][lg * 4 + r][sub * 16 + lr] = f2bf(p);
    }
  };

  auto rel_load = [&](int cA, float (&rA)[4], float (&rB)[4], float& mA, float& mB) {
    int kbA = cA * 128 + w * 16, kbB = kbA + 128;
    #pragma unroll
    for (int r = 0; r < 4; ++r) {
      rA[r] = relbase[(lg * 4 + r) * TOTK + kbA + lr];
      rB[r] = relbase[(lg * 4 + r) * TOTK + kbB + lr];
    }
    mA = mbase[kbA + lr];
    mB = mbase[kbB + lr];
  };

  // one pair (256 keys). rel for CURRENT pair in (rA,rB,mA,mB); prefetch next into (rAn,..)
  auto pair_iter = [&](int p, float (&rA)[4], float (&rB)[4], float& mA, float& mB,
                       float (&rAn)[4], float (&rBn)[4], float& mAn, float& mBn) {
    const int cA = 2 * p;

    // ---- the ONE explicit wait: retire this pair's 8 K-DMAs (oldest) ----
    __builtin_amdgcn_sched_barrier(0);
    asm volatile("s_waitcnt vmcnt(10)" ::: "memory");
    __builtin_amdgcn_sched_barrier(0);

    // ---- issue V for THIS pair (lead time = QK-A + QK-B) ----
    const float* vs = (p < 4) ? ppv + ((n * NH + h) * SS + cA * 128) * DD
                              : pv + ((nb * NH + h) * LL + (cA - 8) * 128) * DD;
    float vraw[32];
    #pragma unroll
    for (int dt = 0; dt < 4; ++dt)
      #pragma unroll
      for (int e = 0; e < 8; ++e) {
        int kslot = lg * 8 + e;
        int j = (kslot >> 4) * 128 + w * 16 + (kslot & 15);
        vraw[dt * 8 + e] = vs[j * DD + dt * 16 + lr];
      }
    __builtin_amdgcn_sched_barrier(0);

    // ---- both QK subs back-to-back (K both resident; rel via auto-wait) ----
    qk_sub(SB, rA, mA, 0);
    qk_sub(SB + 128 * 64, rB, mB, 1);

    // ---- refill both K bufs + next rel, together, before PV ----
    __builtin_amdgcn_sched_barrier(0);
    if (p < 7) {
      kstage(cA + 2, 0);
      kstage(cA + 3, 1);
      rel_load(cA + 2, rAn, rBn, mAn, mBn);
    } else {
      kstage(16, 0);                       // chunk16 -> buf0 (tail)
    }
    __builtin_amdgcn_sched_barrier(0);

    // ---- PV over 32 keys (auto vmcnt retires V only; new DMA/rel stay) ----
    bf16x8 pa = *(const bf16x8*)(&Pb[w][lr][lg * 8]);
    #pragma unroll
    for (int dt = 0; dt < 4; ++dt) {
      BF8 o;
      #pragma unroll
      for (int q = 0; q < 4; ++q)
        o.u[q] = pkbf(vraw[dt * 8 + q * 2], vraw[dt * 8 + q * 2 + 1]);
      ctx[dt] = __builtin_amdgcn_mfma_f32_16x16x32_bf16(pa, o.v, ctx[dt], 0, 0, 0);
    }
  };

  // prologue: stage pair 0 K + rel  -> outstanding = 18, loop invariant holds at p=0
  kstage(0, 0);
  kstage(1, 1);
  float ra0[4], rb0[4], ma0, mb0, ra1[4], rb1[4], ma1, mb1;
  rel_load(0, ra0, rb0, ma0, mb0);
  ma1 = mb1 = 0.f; ra1[0]=ra1[1]=ra1[2]=ra1[3]=0.f; rb1[0]=rb1[1]=rb1[2]=rb1[3]=0.f;

  for (int p = 0; p < 8; p += 2) {
    pair_iter(p,     ra0, rb0, ma0, mb0, ra1, rb1, ma1, mb1);
    pair_iter(p + 1, ra1, rb1, ma1, mb1, ra0, rb0, ma0, mb0);
  }

  // tail: chunk 16 (keys 2048..2063) in buf0; w==0 only, phantom-padded to 32
  if (w == 0) {
    #pragma unroll
    for (int r = 0; r < 4; ++r) Pb[0][lg * 4 + r][16 + lr] = 0;
    const float* vs = vws + ((nb * NH + h) * NT) * DD;
    float vraw[32];
    #pragma unroll
    for (int dt = 0; dt < 4; ++dt)
      #pragma unroll
      for (int e = 0; e < 8; ++e) {
        int kslot = lg * 8 + e;
        vraw[dt * 8 + e] = (kslot < 16) ? vs[kslot * DD + dt * 16 + lr] : 0.f;
      }
    float rrT[4];
    #pragma unroll
    for (int r = 0; r < 4; ++r)
      rrT[r] = relbase[(lg * 4 + r) * TOTK + 2048 + lr];
    float mvT = mbase[2048 + lr];

    __builtin_amdgcn_sched_barrier(0);
    asm volatile("s_waitcnt vmcnt(0)" ::: "memory");
    __builtin_amdgcn_sched_barrier(0);

    qk_sub(SB, rrT, mvT, 0);

    bf16x8 pa = *(const bf16x8*)(&Pb[0][lr][lg * 8]);
    #pragma unroll
    for (int dt = 0; dt < 4; ++dt) {
      BF8 o;
      #pragma unroll
      for (int q = 0; q < 4; ++q)
        o.u[q] = pkbf(vraw[dt * 8 + q * 2], vraw[dt * 8 + q * 2 + 1]);
      ctx[dt] = __builtin_amdgcn_mfma_f32_16x16x32_bf16(pa, o.v, ctx[dt], 0, 0, 0);
    }
  }

  // per-row l reduce across the 16 lanes of each group
  #pragma unroll
  for (int r = 0; r < 4; ++r) {
    #pragma unroll
    for (int o = 8; o >= 1; o >>= 1) ls[r] += __shfl_xor(ls[r], o, 16);
  }

  // merge 8 waves; reuse SB (__syncthreads drains each wave's counters first)
  __syncthreads();
  float* mgc = SB;
  float* mgl = SB + NWAVE * 16 * 64;
  #pragma unroll
  for (int dt = 0; dt < 4; ++dt)
    #pragma unroll
    for (int r = 0; r < 4; ++r)
      mgc[(w * 16 + lg * 4 + r) * 64 + dt * 16 + lr] = ctx[dt][r];
  if (lr == 0) {
    #pragma unroll
    for (int r = 0; r < 4; ++r) mgl[w * 16 + lg * 4 + r] = ls[r];
  }
  __syncthreads();
  #pragma unroll
  for (int i = 0; i < 2; ++i) {
    int idx = i * 512 + tid;
    int t = idx >> 6, d = idx & 63;
    float num = 0.f, den = 0.f;
    #pragma unroll
    for (int ww = 0; ww < NWAVE; ++ww) {
      den += mgl[ww * 16 + t];
      num += mgc[(ww * 16 + t) * 64 + d];
    }
    out[((nb * NT + t) * NH + h) * DD + d] = num / den;
  }
}

extern "C" void kernel_launch(void* const* d_in, const int* in_sizes, int n_in,
                              void* d_out, int out_size, void* d_ws, size_t ws_size,
                              hipStream_t stream) {
  const float* hidden = (const float*)d_in[0];
  const float* mask   = (const float*)d_in[1];
  const float* rel    = (const float*)d_in[2];
  const float* ppk    = (const float*)d_in[3];
  const float* ppv    = (const float*)d_in[4];
  const float* pk     = (const float*)d_in[5];
  const float* pv     = (const float*)d_in[6];
  const float* Wq     = (const float*)d_in[7];
  const float* bq     = (const float*)d_in[8];
  const float* Wk     = (const float*)d_in[9];
  const float* bk     = (const float*)d_in[10];
  const float* Wv     = (const float*)d_in[11];
  const float* bv     = (const float*)d_in[12];
  float* out = (float*)d_out;

  unsigned short* qws = (unsigned short*)d_ws;                 // 1 MB bf16 Q
  float* kws = (float*)((char*)d_ws + (1u << 20));             // 2 MB fp32 new K
  float* vws = (float*)((char*)d_ws + 3u * (1u << 20));        // 2 MB fp32 new V

  proj_kernel<<<dim3(8, 48), 256, 0, stream>>>(hidden, Wq, bq, Wk, bk, Wv, bv,
                                               qws, kws, vws);
  attn_kernel<<<dim3(512), 512, 0, stream>>>(mask, rel, ppk, ppv, pk, pv,
                                             qws, kws, vws, out);
}